// Round 14
// baseline (583.169 us; speedup 1.0000x reference)
//
#include <hip/hip_runtime.h>

// EncoderSRNN: T=256 steps, B=128, HDIM=EDIM=256, SSZ=64, SDIM=64, SDEPTH=2, NACT=3
#define T_STEPS 256
#define BATCH 128

// ws float offsets (transposed weights + combined bias)
#define WEHT_OFF 0         // [e][h] 256x256
#define WHHT_OFF 65536     // [e][h] 256x256
#define WSHT_OFF 131072    // [j][h] 128x256
#define WHST_OFF 163840    // [e][s] 256x64
#define WSUT_OFF 180224    // [j][s] 128x64
#define BC_OFF   188416    // bc[h] = b_eh+b_hh+b_sh

#define HID_OFF   8388608
#define STACK_OFF 8421376
#define ACTS_OFF  8945664

typedef __attribute__((ext_vector_type(2))) float f32x2;

// In-loop barrier: LDS-only fence + raw barrier (no vmcnt drain; all cross-wave
// handoffs are DS ops, all global ops in the loop are same-thread ordered).
#define BAR_LDS() do { \
    asm volatile("s_waitcnt lgkmcnt(0)" ::: "memory"); \
    __builtin_amdgcn_s_barrier(); \
} while (0)

// broadcast lane l of v to all lanes via SGPR (VALU pipe, NOT the LDS unit).
// MUST be called in uniform (full-exec) control flow: under a divergent branch
// the allocator may insert exec-masked copies of v, leaving other lanes' copy
// garbage (r13 failure: rl() inside if(lane==0) -> scal garbage -> 1e17 blowup).
__device__ __forceinline__ float rl(float v, int l) {
    return __int_as_float(__builtin_amdgcn_readlane(__float_as_int(v), l));
}

// ---------------- kernel 0: transpose weights into ws, fold biases ----------
__global__ __launch_bounds__(256) void prep_kernel(
    const float* __restrict__ W_hh, const float* __restrict__ b_hh,
    const float* __restrict__ W_eh, const float* __restrict__ b_eh,
    const float* __restrict__ W_sh, const float* __restrict__ b_sh,
    const float* __restrict__ W_hs, const float* __restrict__ W_su,
    float* __restrict__ ws)
{
    int idx = blockIdx.x * 256 + threadIdx.x;
    if (idx < 65536) {                       // W_ehT[e][h] = W_eh[h][e]
        ws[WEHT_OFF + idx] = W_eh[(idx & 255) * 256 + (idx >> 8)];
    } else if (idx < 131072) {               // W_hhT
        int k = idx - 65536;
        ws[WHHT_OFF + k] = W_hh[(k & 255) * 256 + (k >> 8)];
    } else if (idx < 163840) {               // W_shT[j][h] = W_sh[h][j]
        int k = idx - 131072;
        ws[WSHT_OFF + k] = W_sh[(k & 255) * 128 + (k >> 8)];
    } else if (idx < 180224) {               // W_hsT[e][s] = W_hs[s][e]
        int k = idx - 163840;
        ws[WHST_OFF + k] = W_hs[(k & 63) * 256 + (k >> 6)];
    } else if (idx < 188416) {               // W_suT[j][s] = W_su[s][j]
        int k = idx - 180224;
        ws[WSUT_OFF + k] = W_su[(k & 63) * 128 + (k >> 6)];
    } else if (idx < 188672) {
        int k = idx - 188416;
        ws[BC_OFF + k] = b_eh[k] + b_hh[k] + b_sh[k];
    }
}

// ---------------- kernel 1: ex[t,b,h] = emb_W[tok]@W_eh.T + bc  -------------
// v2 (proven fastest across v1-v4 by the cross-round gap series: v1 145-156us,
// v2 126us, v3 141us, v4 148us). Uniform b128 LDS reads are same-address
// broadcasts -> conflict-free and cheap. 8 rows x 4 cols per thread; per e:
// 2 uniform b128 (emb) + 1 coalesced global b128 (weights, L2) + 32 FMA.
__global__ __launch_bounds__(256) void ex_gemm(
    const int* __restrict__ tokens, const float* __restrict__ emb_W,
    const float* __restrict__ ws, float* __restrict__ outp)
{
    __shared__ __align__(16) float aT[64 * 40];   // [e][row], stride 40
    __shared__ int tok[32];
    const int t = threadIdx.x;
    const int rg = t >> 6;         // row group: rows rg*8 .. rg*8+7
    const int c0 = (t & 63) * 4;   // 4 contiguous cols
    const int R0 = blockIdx.x * 32;
    if (t < 32) tok[t] = tokens[R0 + t];
    __syncthreads();

    float acc[8][4];
#pragma unroll
    for (int r = 0; r < 8; r++)
#pragma unroll
        for (int c = 0; c < 4; c++) acc[r][c] = 0.f;

    for (int e0 = 0; e0 < 256; e0 += 64) {
        {
            int r = t >> 3, seg = t & 7;
            const float* src = emb_W + (size_t)tok[r] * 256 + e0 + seg * 8;
            float4 v0 = *(const float4*)(src);
            float4 v1 = *(const float4*)(src + 4);
            int eb = seg * 8;
            aT[(eb + 0) * 40 + r] = v0.x; aT[(eb + 1) * 40 + r] = v0.y;
            aT[(eb + 2) * 40 + r] = v0.z; aT[(eb + 3) * 40 + r] = v0.w;
            aT[(eb + 4) * 40 + r] = v1.x; aT[(eb + 5) * 40 + r] = v1.y;
            aT[(eb + 6) * 40 + r] = v1.z; aT[(eb + 7) * 40 + r] = v1.w;
        }
        __syncthreads();
        const float* wp = ws + WEHT_OFF + (size_t)e0 * 256 + c0;
#pragma unroll 2
        for (int e = 0; e < 64; e++) {
            float4 wv = *(const float4*)(wp + (size_t)e * 256);  // coalesced, L2
            const float* ar = &aT[e * 40 + rg * 8];
            float4 a0 = *(const float4*)(ar);                    // rows rg*8..+3
            float4 a1 = *(const float4*)(ar + 4);                // rows rg*8+4..+7
            acc[0][0] = fmaf(a0.x, wv.x, acc[0][0]); acc[0][1] = fmaf(a0.x, wv.y, acc[0][1]);
            acc[0][2] = fmaf(a0.x, wv.z, acc[0][2]); acc[0][3] = fmaf(a0.x, wv.w, acc[0][3]);
            acc[1][0] = fmaf(a0.y, wv.x, acc[1][0]); acc[1][1] = fmaf(a0.y, wv.y, acc[1][1]);
            acc[1][2] = fmaf(a0.y, wv.z, acc[1][2]); acc[1][3] = fmaf(a0.y, wv.w, acc[1][3]);
            acc[2][0] = fmaf(a0.z, wv.x, acc[2][0]); acc[2][1] = fmaf(a0.z, wv.y, acc[2][1]);
            acc[2][2] = fmaf(a0.z, wv.z, acc[2][2]); acc[2][3] = fmaf(a0.z, wv.w, acc[2][3]);
            acc[3][0] = fmaf(a0.w, wv.x, acc[3][0]); acc[3][1] = fmaf(a0.w, wv.y, acc[3][1]);
            acc[3][2] = fmaf(a0.w, wv.z, acc[3][2]); acc[3][3] = fmaf(a0.w, wv.w, acc[3][3]);
            acc[4][0] = fmaf(a1.x, wv.x, acc[4][0]); acc[4][1] = fmaf(a1.x, wv.y, acc[4][1]);
            acc[4][2] = fmaf(a1.x, wv.z, acc[4][2]); acc[4][3] = fmaf(a1.x, wv.w, acc[4][3]);
            acc[5][0] = fmaf(a1.y, wv.x, acc[5][0]); acc[5][1] = fmaf(a1.y, wv.y, acc[5][1]);
            acc[5][2] = fmaf(a1.y, wv.z, acc[5][2]); acc[5][3] = fmaf(a1.y, wv.w, acc[5][3]);
            acc[6][0] = fmaf(a1.z, wv.x, acc[6][0]); acc[6][1] = fmaf(a1.z, wv.y, acc[6][1]);
            acc[6][2] = fmaf(a1.z, wv.z, acc[6][2]); acc[6][3] = fmaf(a1.z, wv.w, acc[6][3]);
            acc[7][0] = fmaf(a1.w, wv.x, acc[7][0]); acc[7][1] = fmaf(a1.w, wv.y, acc[7][1]);
            acc[7][2] = fmaf(a1.w, wv.z, acc[7][2]); acc[7][3] = fmaf(a1.w, wv.w, acc[7][3]);
        }
        __syncthreads();
    }
    float4 bc4 = *(const float4*)&ws[BC_OFF + c0];
#pragma unroll
    for (int r = 0; r < 8; r++) {
        float4 o;
        o.x = acc[r][0] + bc4.x; o.y = acc[r][1] + bc4.y;
        o.z = acc[r][2] + bc4.z; o.w = acc[r][3] + bc4.w;
        *(float4*)&outp[(size_t)(R0 + rg * 8 + r) * 256 + c0] = o;
    }
}

// ---------------- kernel 2: sequential scan, 2 LDS-only barriers/step -------
// r12 base + phase-B reduce shortened, readlane-divergence FIXED: the 4-way
// block-sum combine (rl of lanes 0/16/32/48) now executes UNCONDITIONALLY in
// the wave-uniform w<4 region (full exec); only the scal store is lane-gated.
__attribute__((amdgpu_flat_work_group_size(512, 512)))
__attribute__((amdgpu_waves_per_eu(2, 2)))
__global__ void rnn_scan(
    const float* __restrict__ ws,
    const float* __restrict__ W_ha, const float* __restrict__ b_ha,
    const float* __restrict__ W_hg, const float* __restrict__ b_hg,
    const float* __restrict__ b_hs, const float* __restrict__ b_su,
    const float* __restrict__ empty_elem,
    float* __restrict__ out)
{
    __shared__ __align__(16) float hid[256];
    __shared__ __align__(16) float tops[128];
    __shared__ __align__(16) float partial[8 * 256]; // 8 KB
    __shared__ __align__(16) float2 pp2[8 * 64];     // 4 KB {accP, accU}
    __shared__ __align__(16) float bnd[16 * 64];     // old boundary rows
    __shared__ __align__(16) float wsu_l[8192];      // 32 KB, packed [j>>2][s][j&3]
    __shared__ __align__(16) float whs_l[16384];     // 64 KB, packed [e>>2][s][e&3]
    __shared__ __align__(16) float whaL[1024];       // rows 0-2: W_ha, row 3: W_hg
    __shared__ __align__(16) float scal[4];

    const int t = threadIdx.x, lane = t & 63, w = t >> 6;
    const int b = blockIdx.x;

    // ---- weight registers as aligned pairs (loaded once, liveness-pinned)
    f32x2 whh2[64], wsh2[32];
    {
        const float* base = ws + WHHT_OFF + (size_t)(w * 32) * 256 + lane * 4;
#pragma unroll
        for (int e = 0; e < 32; e++) {
            float4 v = *(const float4*)(base + (size_t)e * 256);
            whh2[2 * e]     = (f32x2){v.x, v.y};
            whh2[2 * e + 1] = (f32x2){v.z, v.w};
        }
        const float* base2 = ws + WSHT_OFF + (size_t)(w * 16) * 256 + lane * 4;
#pragma unroll
        for (int j = 0; j < 16; j++) {
            float4 v = *(const float4*)(base2 + (size_t)j * 256);
            wsh2[2 * j]     = (f32x2){v.x, v.y};
            wsh2[2 * j + 1] = (f32x2){v.z, v.w};
        }
    }
    // pin: opaque 64-bit defs -> not rematerializable, pair-aligned, live on-chip
#pragma unroll
    for (int i = 0; i < 64; i++) asm volatile("" : "+v"(whh2[i]));
#pragma unroll
    for (int i = 0; i < 32; i++) asm volatile("" : "+v"(wsh2[i]));

    // per-role bias registers
    float bscal = 0.f;
    if (lane == 0 && w < 4) bscal = (w < 3) ? b_ha[w] : b_hg[0];
    float bhs_r = 0.f, bsu_r = 0.f;
    if (w == 0) { bhs_r = b_hs[lane]; bsu_r = b_su[lane]; }

    // ---- init state: stack rows in registers, weights + small state in LDS
    const float ev = empty_elem[lane];
    float sv[8];
#pragma unroll
    for (int k = 0; k < 8; k++) sv[k] = ev;
    if (t < 256) hid[t] = 0.f;
    if (t < 128) tops[t] = empty_elem[t & 63];
    bnd[(w * 2) * 64 + lane] = ev;
    bnd[(w * 2 + 1) * 64 + lane] = ev;
    // whs packed quads: src i = e*64+s -> dst (e>>2)*256 + s*4 + (e&3)
    for (int i = t; i < 16384; i += 512)
        whs_l[(i >> 8) * 256 + (i & 63) * 4 + ((i >> 6) & 3)] = ws[WHST_OFF + i];
    for (int i = t; i < 8192; i += 512) {
        int j = i >> 6, s = i & 63;
        wsu_l[(j >> 2) * 256 + s * 4 + (j & 3)] = ws[WSUT_OFF + i];
    }
    for (int i = t; i < 1024; i += 512)
        whaL[i] = (i < 768) ? W_ha[i] : W_hg[i - 768];
    __syncthreads();   // full barrier once (drains init global loads too)

    // combined slice source: lanes 0-31 read this wave's hid slice,
    // lanes 32-47 its tops slice (48-63 duplicate; same-addr broadcast is free)
    const float* slice_ptr = (lane < 32) ? &hid[w * 32 + lane]
                                         : &tops[w * 16 + (lane & 15)];

    // ex double-buffer: preload step 0 (waves 4-7 own hid elem h = t-256)
    float exv = (w >= 4) ? out[(size_t)b * 256 + (t - 256)] : 0.f;

    const float4* whs4 = (const float4*)whs_l;  // [(e>>2)*64 + s]
    const float4* wsu4 = (const float4*)wsu_l;  // [(j>>2)*64 + s]

    for (int ts = 0; ts < T_STEPS; ts++) {
        // prefetch NEXT step's ex (full step of latency cover, no vmcnt at barriers)
        float exn = 0.f;
        if (w >= 4 && ts + 1 < T_STEPS)
            exn = out[((size_t)(ts + 1) * BATCH + b) * 256 + (t - 256)];

        // halo reads: neighbors' OLD boundary rows (published last step)
        float halo_lo = (w == 0) ? 0.f : bnd[((w - 1) * 2 + 1) * 64 + lane]; // row w*8-1
        float halo_hi = (w == 7) ? 0.f : bnd[((w + 1) * 2) * 64 + lane];     // row w*8+8

        // ======== phase A: 1 spread b32 (state) + 8 b128 (whs) + 4 b128 (wsu)
        float slice = *slice_ptr;   // ds_read_b32, full-BW spread
        f32x2 acc01 = (f32x2){0.f, 0.f}, acc23 = (f32x2){0.f, 0.f};
        float accP = 0.f, accU = 0.f;
#pragma unroll
        for (int eb = 0; eb < 8; eb++) {
            float4 sp = whs4[(w * 8 + eb) * 64 + lane];   // spread b128
            float h0 = rl(slice, 4 * eb + 0);
            float h1 = rl(slice, 4 * eb + 1);
            float h2 = rl(slice, 4 * eb + 2);
            float h3 = rl(slice, 4 * eb + 3);
            f32x2 h0v = {h0, h0}, h1v = {h1, h1}, h2v = {h2, h2}, h3v = {h3, h3};
            acc01 = __builtin_elementwise_fma(whh2[(4*eb+0)*2],   h0v, acc01);
            acc23 = __builtin_elementwise_fma(whh2[(4*eb+0)*2+1], h0v, acc23);
            acc01 = __builtin_elementwise_fma(whh2[(4*eb+1)*2],   h1v, acc01);
            acc23 = __builtin_elementwise_fma(whh2[(4*eb+1)*2+1], h1v, acc23);
            acc01 = __builtin_elementwise_fma(whh2[(4*eb+2)*2],   h2v, acc01);
            acc23 = __builtin_elementwise_fma(whh2[(4*eb+2)*2+1], h2v, acc23);
            acc01 = __builtin_elementwise_fma(whh2[(4*eb+3)*2],   h3v, acc01);
            acc23 = __builtin_elementwise_fma(whh2[(4*eb+3)*2+1], h3v, acc23);
            accP = fmaf(sp.x, h0, accP);
            accP = fmaf(sp.y, h1, accP);
            accP = fmaf(sp.z, h2, accP);
            accP = fmaf(sp.w, h3, accP);
        }
#pragma unroll
        for (int jb = 0; jb < 4; jb++) {
            float4 su = wsu4[(w * 4 + jb) * 64 + lane];   // spread b128
            float tv0 = rl(slice, 32 + 4 * jb);
            float tv1 = rl(slice, 32 + 4 * jb + 1);
            float tv2 = rl(slice, 32 + 4 * jb + 2);
            float tv3 = rl(slice, 32 + 4 * jb + 3);
            f32x2 t0v = {tv0, tv0}, t1v = {tv1, tv1}, t2v = {tv2, tv2}, t3v = {tv3, tv3};
            acc01 = __builtin_elementwise_fma(wsh2[(4*jb+0)*2],   t0v, acc01);
            acc23 = __builtin_elementwise_fma(wsh2[(4*jb+0)*2+1], t0v, acc23);
            acc01 = __builtin_elementwise_fma(wsh2[(4*jb+1)*2],   t1v, acc01);
            acc23 = __builtin_elementwise_fma(wsh2[(4*jb+1)*2+1], t1v, acc23);
            acc01 = __builtin_elementwise_fma(wsh2[(4*jb+2)*2],   t2v, acc01);
            acc23 = __builtin_elementwise_fma(wsh2[(4*jb+2)*2+1], t2v, acc23);
            acc01 = __builtin_elementwise_fma(wsh2[(4*jb+3)*2],   t3v, acc01);
            acc23 = __builtin_elementwise_fma(wsh2[(4*jb+3)*2+1], t3v, acc23);
            accU = fmaf(su.x, tv0, accU);
            accU = fmaf(su.y, tv1, accU);
            accU = fmaf(su.z, tv2, accU);
            accU = fmaf(su.w, tv3, accU);
        }
        *(float4*)&partial[w * 256 + lane * 4] =
            make_float4(acc01.x, acc01.y, acc23.x, acc23.y);
        pp2[w * 64 + lane] = make_float2(accP, accU);   // one b64 write

        // ======== phase B: act logits + gamma dots (waves 0..3, old hid)
        // shortened reduce: 4 shuffles within 16-lane blocks; the 16-block sums
        // (lanes 0/16/32/48) combined via readlanes executed in FULL-EXEC
        // context (wave-uniform w<4) — the r13 failure was these rl() calls
        // sitting inside the divergent lane==0 branch.
        if (w < 4) {
            float bd = 0.f;
#pragma unroll
            for (int k = 0; k < 4; k++)
                bd = fmaf(whaL[w * 256 + k * 64 + lane], hid[k * 64 + lane], bd);
            bd += __shfl_down(bd, 8);
            bd += __shfl_down(bd, 4);
            bd += __shfl_down(bd, 2);
            bd += __shfl_down(bd, 1);
            float bsum = rl(bd, 0) + rl(bd, 16) + rl(bd, 32) + rl(bd, 48);
            if (lane == 0) scal[w] = bsum + bscal;
        }
        BAR_LDS(); // s1: partials + pp2 + scal visible; all old-state reads done

        // ---- wave 0 alone: push/pop values (only consumed by stack row 0)
        float pvv = 0.f, uvv = 0.f;
        if (w == 0) {
            float v1 = bhs_r, v2 = bsu_r;
#pragma unroll
            for (int q = 0; q < 8; q++) {
                float2 pq = pp2[q * 64 + lane];        // b64 reads
                v1 += pq.x; v2 += pq.y;
            }
            pvv = fmaxf(v1, 0.f);
            uvv = fmaxf(v2, 0.f);
        }

        // ---- hid reduce (waves 4..7 own one h each)
        if (w >= 4) {
            int h = t - 256;
            float mh = exv;
#pragma unroll
            for (int q = 0; q < 8; q++) mh += partial[q * 256 + h];
            float nh = fmaxf(mh, 0.f);
            hid[h] = nh;
            out[((size_t)ts * BATCH + b) * 256 + h] = nh;
        }

        // ---- softmax -> sharpen (fast transcendentals; all threads redundant)
        float4 sc4 = *(const float4*)scal;             // one b128
        float l0 = sc4.x, l1 = sc4.y, l2 = sc4.z, gv = sc4.w;
        float eg = __expf(gv);
        float g = 1.f + ((gv > 15.f) ? gv : __logf(1.f + eg));
        float m = fmaxf(l0, fmaxf(l1, l2));
        float z = __expf(l0 - m) + __expf(l1 - m) + __expf(l2 - m);
        float lz = __logf(z);
        float s0  = __expf(g * (l0 - m - lz));
        float s1v = __expf(g * (l1 - m - lz));
        float s2v = __expf(g * (l2 - m - lz));
        float S = s0 + s1v + s2v + 1e-16f;
        float rS = __builtin_amdgcn_rcpf(S);
        float p0 = s0 * rS, p1 = s1v * rS, p2 = s2v * rS;

        if (t == 0) {
            int am = 0; float bm = s0;
            if (s1v > bm) { bm = s1v; am = 1; }
            if (s2v > bm) { bm = s2v; am = 2; }
            out[ACTS_OFF + ts * BATCH + b] = (float)am;
        }

        // ---- stack blend fully in registers
        {
            float nv[8];
            float below0 = (w == 0) ? pvv : halo_lo;     // push src for row w*8
            float pop0   = (w == 0) ? uvv : sv[1];       // pop src (row 0 gets u_val)
            nv[0] = fmaf(p0, below0, fmaf(p1, pop0, p2 * sv[0]));
#pragma unroll
            for (int k = 1; k < 7; k++)
                nv[k] = fmaf(p0, sv[k - 1], fmaf(p1, sv[k + 1], p2 * sv[k]));
            nv[7] = fmaf(p0, sv[6], fmaf(p1, halo_hi, p2 * sv[7]));
#pragma unroll
            for (int k = 0; k < 8; k++) sv[k] = nv[k];
        }
        // publish new boundary rows (next step's "old" halo) + tops
        bnd[(w * 2) * 64 + lane] = sv[0];
        bnd[(w * 2 + 1) * 64 + lane] = sv[7];
        if (w == 0) { tops[lane] = sv[0]; tops[64 + lane] = sv[1]; }

        exv = exn;
        BAR_LDS(); // s2: new hid/tops/bnd visible for next step
    }

    // ---- final hid & stack
    if (t < 256) out[HID_OFF + (size_t)b * 256 + t] = hid[t];
#pragma unroll
    for (int k = 0; k < 8; k++)
        out[STACK_OFF + (size_t)b * 4096 + (w * 8 + k) * 64 + lane] = sv[k];
}

// ---------------- launcher ---------------------------------------------------
extern "C" void kernel_launch(void* const* d_in, const int* in_sizes, int n_in,
                              void* d_out, int out_size, void* d_ws, size_t ws_size,
                              hipStream_t stream)
{
    (void)in_sizes; (void)n_in; (void)out_size; (void)ws_size;
    const int*   inputs     = (const int*)d_in[0];
    const float* emb_W      = (const float*)d_in[1];
    const float* W_hh       = (const float*)d_in[2];
    const float* b_hh       = (const float*)d_in[3];
    const float* W_eh       = (const float*)d_in[4];
    const float* b_eh       = (const float*)d_in[5];
    const float* W_ha       = (const float*)d_in[6];
    const float* b_ha       = (const float*)d_in[7];
    const float* W_hg       = (const float*)d_in[8];
    const float* b_hg       = (const float*)d_in[9];
    const float* W_hs       = (const float*)d_in[10];
    const float* b_hs       = (const float*)d_in[11];
    const float* W_sh       = (const float*)d_in[12];
    const float* b_sh       = (const float*)d_in[13];
    const float* W_su       = (const float*)d_in[14];
    const float* b_su       = (const float*)d_in[15];
    const float* empty_elem = (const float*)d_in[16];
    float* out = (float*)d_out;
    float* ws  = (float*)d_ws;

    hipLaunchKernelGGL(prep_kernel, dim3(737), dim3(256), 0, stream,
                       W_hh, b_hh, W_eh, b_eh, W_sh, b_sh, W_hs, W_su, ws);
    hipLaunchKernelGGL(ex_gemm, dim3(1024), dim3(256), 0, stream,
                       inputs, emb_W, ws, out);
    hipLaunchKernelGGL(rnn_scan, dim3(128), dim3(512), 0, stream,
                       ws, W_ha, b_ha, W_hg, b_hg, b_hs, b_su, empty_elem, out);
}

// Round 16
// 569.799 us; speedup vs baseline: 1.0235x; 1.0235x over previous
//
#include <hip/hip_runtime.h>

// EncoderSRNN: T=256 steps, B=128, HDIM=EDIM=256, SSZ=64, SDIM=64, SDEPTH=2, NACT=3
#define T_STEPS 256
#define BATCH 128

// ws float offsets (transposed weights + combined bias)
#define WEHT_OFF 0         // [e][h] 256x256
#define WHHT_OFF 65536     // [e][h] 256x256
#define WSHT_OFF 131072    // [j][h] 128x256
#define WHST_OFF 163840    // [e][s] 256x64
#define WSUT_OFF 180224    // [j][s] 128x64
#define BC_OFF   188416    // bc[h] = b_eh+b_hh+b_sh

#define HID_OFF   8388608
#define STACK_OFF 8421376
#define ACTS_OFF  8945664

typedef __attribute__((ext_vector_type(2))) float f32x2;

// In-loop barrier: LDS-only fence + raw barrier (no vmcnt drain; all cross-wave
// handoffs are DS ops, all global ops in the loop are same-thread ordered).
#define BAR_LDS() do { \
    asm volatile("s_waitcnt lgkmcnt(0)" ::: "memory"); \
    __builtin_amdgcn_s_barrier(); \
} while (0)

// broadcast lane l of v to all lanes via SGPR (VALU pipe, NOT the LDS unit).
// MUST be called in uniform (full-exec) control flow (r13 lesson).
__device__ __forceinline__ float rl(float v, int l) {
    return __int_as_float(__builtin_amdgcn_readlane(__float_as_int(v), l));
}

// ---------------- kernel 0: transpose weights into ws, fold biases ----------
__global__ __launch_bounds__(256) void prep_kernel(
    const float* __restrict__ W_hh, const float* __restrict__ b_hh,
    const float* __restrict__ W_eh, const float* __restrict__ b_eh,
    const float* __restrict__ W_sh, const float* __restrict__ b_sh,
    const float* __restrict__ W_hs, const float* __restrict__ W_su,
    float* __restrict__ ws)
{
    int idx = blockIdx.x * 256 + threadIdx.x;
    if (idx < 65536) {                       // W_ehT[e][h] = W_eh[h][e]
        ws[WEHT_OFF + idx] = W_eh[(idx & 255) * 256 + (idx >> 8)];
    } else if (idx < 131072) {               // W_hhT
        int k = idx - 65536;
        ws[WHHT_OFF + k] = W_hh[(k & 255) * 256 + (k >> 8)];
    } else if (idx < 163840) {               // W_shT[j][h] = W_sh[h][j]
        int k = idx - 131072;
        ws[WSHT_OFF + k] = W_sh[(k & 255) * 128 + (k >> 8)];
    } else if (idx < 180224) {               // W_hsT[e][s] = W_hs[s][e]
        int k = idx - 163840;
        ws[WHST_OFF + k] = W_hs[(k & 63) * 256 + (k >> 6)];
    } else if (idx < 188416) {               // W_suT[j][s] = W_su[s][j]
        int k = idx - 180224;
        ws[WSUT_OFF + k] = W_su[(k & 63) * 128 + (k >> 6)];
    } else if (idx < 188672) {
        int k = idx - 188416;
        ws[BC_OFF + k] = b_eh[k] + b_hh[k] + b_sh[k];
    }
}

// ---------------- kernel 1: ex[t,b,h] = emb_W[tok]@W_eh.T + bc  -------------
// v4 (r12 configuration — best measured total). Cooperative coalesced staging
// of the 32x64 emb chunk into LDS, then 8 spread ds_read_b32 per thread and
// readlane broadcasts feeding pk-fma. Ex-version choice is within cross-round
// noise (±15us); r12's combo is the proven-best total.
__global__ __launch_bounds__(256) void ex_gemm(
    const int* __restrict__ tokens, const float* __restrict__ emb_W,
    const float* __restrict__ ws, float* __restrict__ outp)
{
    __shared__ __align__(16) float aT[32 * 68];   // [row][e], stride 68
    __shared__ int tok[32];
    const int t = threadIdx.x, lane = t & 63, rg = t >> 6;
    const int c0 = lane * 4;
    const int R0 = blockIdx.x * 32;
    if (t < 32) tok[t] = tokens[R0 + t];
    __syncthreads();

    f32x2 accA[8], accB[8];
#pragma unroll
    for (int r = 0; r < 8; r++) {
        accA[r] = (f32x2){0.f, 0.f};
        accB[r] = (f32x2){0.f, 0.f};
    }

    for (int e0 = 0; e0 < 256; e0 += 64) {
        {   // cooperative stage: thread t loads row=t>>3, cols seg*8..+8 (coalesced)
            int row = t >> 3, seg = t & 7;
            const float* src = emb_W + (size_t)tok[row] * 256 + e0 + seg * 8;
            float4 v0 = *(const float4*)(src);
            float4 v1 = *(const float4*)(src + 4);
            float* dst = &aT[row * 68 + seg * 8];
            *(float4*)(dst) = v0;          // 16B-aligned (272*row + 32*seg)
            *(float4*)(dst + 4) = v1;
        }
        __syncthreads();
        // spread read: lane l holds col l of each of this wave's 8 rows
        float er[8];
#pragma unroll
        for (int r = 0; r < 8; r++) er[r] = aT[(rg * 8 + r) * 68 + lane];

        const float* wp = ws + WEHT_OFF + (size_t)e0 * 256 + c0;
#pragma unroll
        for (int e = 0; e < 64; e++) {
            float4 wv = *(const float4*)(wp + (size_t)e * 256);  // coalesced, L2
            f32x2 w01 = {wv.x, wv.y}, w23 = {wv.z, wv.w};
#pragma unroll
            for (int r = 0; r < 8; r++) {
                float a = rl(er[r], e);
                f32x2 av = {a, a};
                accA[r] = __builtin_elementwise_fma(w01, av, accA[r]);
                accB[r] = __builtin_elementwise_fma(w23, av, accB[r]);
            }
        }
        __syncthreads();   // all er reads in regs; safe to overwrite aT
    }
    float4 bc4 = *(const float4*)&ws[BC_OFF + c0];
#pragma unroll
    for (int r = 0; r < 8; r++) {
        float4 o;
        o.x = accA[r].x + bc4.x; o.y = accA[r].y + bc4.y;
        o.z = accB[r].x + bc4.z; o.w = accB[r].y + bc4.w;
        *(float4*)&outp[(size_t)(R0 + rg * 8 + r) * 256 + c0] = o;
    }
}

// ---------------- kernel 2: sequential scan, 2 LDS-only barriers/step -------
// r12 EXACT (proven 424us scan / 571us total — session best). Final config:
//   - 192 regs/thread pinned via empty asm(+v) as pair-aligned f32x2 so the
//     dominant FMA stream compiles to v_pk_fma_f32 (2x fp32 rate)
//   - state broadcast: ONE spread ds_read_b32 + readlane (SGPR, VALU pipe)
//   - whs/wsu packed in LDS for spread b128 reads
//   - LDS-only barriers (no vmcnt drain); ex double-buffered across steps
//   - phase B: plain 6-deep shuffle chain (r14's shortened variant was +2.6%)
// Structural floor: latency-bound recurrence; VALU issue ~saturated in active
// phases; 1024-thread occupancy (128-reg budget < 192 pins) and transposed
// h-ownership (readlane can't do per-lane-group broadcasts) both refuted.
__attribute__((amdgpu_flat_work_group_size(512, 512)))
__attribute__((amdgpu_waves_per_eu(2, 2)))
__global__ void rnn_scan(
    const float* __restrict__ ws,
    const float* __restrict__ W_ha, const float* __restrict__ b_ha,
    const float* __restrict__ W_hg, const float* __restrict__ b_hg,
    const float* __restrict__ b_hs, const float* __restrict__ b_su,
    const float* __restrict__ empty_elem,
    float* __restrict__ out)
{
    __shared__ __align__(16) float hid[256];
    __shared__ __align__(16) float tops[128];
    __shared__ __align__(16) float partial[8 * 256]; // 8 KB
    __shared__ __align__(16) float2 pp2[8 * 64];     // 4 KB {accP, accU}
    __shared__ __align__(16) float bnd[16 * 64];     // old boundary rows
    __shared__ __align__(16) float wsu_l[8192];      // 32 KB, packed [j>>2][s][j&3]
    __shared__ __align__(16) float whs_l[16384];     // 64 KB, packed [e>>2][s][e&3]
    __shared__ __align__(16) float whaL[1024];       // rows 0-2: W_ha, row 3: W_hg
    __shared__ __align__(16) float scal[4];

    const int t = threadIdx.x, lane = t & 63, w = t >> 6;
    const int b = blockIdx.x;

    // ---- weight registers as aligned pairs (loaded once, liveness-pinned)
    f32x2 whh2[64], wsh2[32];
    {
        const float* base = ws + WHHT_OFF + (size_t)(w * 32) * 256 + lane * 4;
#pragma unroll
        for (int e = 0; e < 32; e++) {
            float4 v = *(const float4*)(base + (size_t)e * 256);
            whh2[2 * e]     = (f32x2){v.x, v.y};
            whh2[2 * e + 1] = (f32x2){v.z, v.w};
        }
        const float* base2 = ws + WSHT_OFF + (size_t)(w * 16) * 256 + lane * 4;
#pragma unroll
        for (int j = 0; j < 16; j++) {
            float4 v = *(const float4*)(base2 + (size_t)j * 256);
            wsh2[2 * j]     = (f32x2){v.x, v.y};
            wsh2[2 * j + 1] = (f32x2){v.z, v.w};
        }
    }
    // pin: opaque 64-bit defs -> not rematerializable, pair-aligned, live on-chip
#pragma unroll
    for (int i = 0; i < 64; i++) asm volatile("" : "+v"(whh2[i]));
#pragma unroll
    for (int i = 0; i < 32; i++) asm volatile("" : "+v"(wsh2[i]));

    // per-role bias registers
    float bscal = 0.f;
    if (lane == 0 && w < 4) bscal = (w < 3) ? b_ha[w] : b_hg[0];
    float bhs_r = 0.f, bsu_r = 0.f;
    if (w == 0) { bhs_r = b_hs[lane]; bsu_r = b_su[lane]; }

    // ---- init state: stack rows in registers, weights + small state in LDS
    const float ev = empty_elem[lane];
    float sv[8];
#pragma unroll
    for (int k = 0; k < 8; k++) sv[k] = ev;
    if (t < 256) hid[t] = 0.f;
    if (t < 128) tops[t] = empty_elem[t & 63];
    bnd[(w * 2) * 64 + lane] = ev;
    bnd[(w * 2 + 1) * 64 + lane] = ev;
    // whs packed quads: src i = e*64+s -> dst (e>>2)*256 + s*4 + (e&3)
    for (int i = t; i < 16384; i += 512)
        whs_l[(i >> 8) * 256 + (i & 63) * 4 + ((i >> 6) & 3)] = ws[WHST_OFF + i];
    for (int i = t; i < 8192; i += 512) {
        int j = i >> 6, s = i & 63;
        wsu_l[(j >> 2) * 256 + s * 4 + (j & 3)] = ws[WSUT_OFF + i];
    }
    for (int i = t; i < 1024; i += 512)
        whaL[i] = (i < 768) ? W_ha[i] : W_hg[i - 768];
    __syncthreads();   // full barrier once (drains init global loads too)

    // combined slice source: lanes 0-31 read this wave's hid slice,
    // lanes 32-47 its tops slice (48-63 duplicate; same-addr broadcast is free)
    const float* slice_ptr = (lane < 32) ? &hid[w * 32 + lane]
                                         : &tops[w * 16 + (lane & 15)];

    // ex double-buffer: preload step 0 (waves 4-7 own hid elem h = t-256)
    float exv = (w >= 4) ? out[(size_t)b * 256 + (t - 256)] : 0.f;

    const float4* whs4 = (const float4*)whs_l;  // [(e>>2)*64 + s]
    const float4* wsu4 = (const float4*)wsu_l;  // [(j>>2)*64 + s]

    for (int ts = 0; ts < T_STEPS; ts++) {
        // prefetch NEXT step's ex (full step of latency cover, no vmcnt at barriers)
        float exn = 0.f;
        if (w >= 4 && ts + 1 < T_STEPS)
            exn = out[((size_t)(ts + 1) * BATCH + b) * 256 + (t - 256)];

        // halo reads: neighbors' OLD boundary rows (published last step)
        float halo_lo = (w == 0) ? 0.f : bnd[((w - 1) * 2 + 1) * 64 + lane]; // row w*8-1
        float halo_hi = (w == 7) ? 0.f : bnd[((w + 1) * 2) * 64 + lane];     // row w*8+8

        // ======== phase A: 1 spread b32 (state) + 8 b128 (whs) + 4 b128 (wsu)
        float slice = *slice_ptr;   // ds_read_b32, full-BW spread
        f32x2 acc01 = (f32x2){0.f, 0.f}, acc23 = (f32x2){0.f, 0.f};
        float accP = 0.f, accU = 0.f;
#pragma unroll
        for (int eb = 0; eb < 8; eb++) {
            float4 sp = whs4[(w * 8 + eb) * 64 + lane];   // spread b128
            float h0 = rl(slice, 4 * eb + 0);
            float h1 = rl(slice, 4 * eb + 1);
            float h2 = rl(slice, 4 * eb + 2);
            float h3 = rl(slice, 4 * eb + 3);
            f32x2 h0v = {h0, h0}, h1v = {h1, h1}, h2v = {h2, h2}, h3v = {h3, h3};
            acc01 = __builtin_elementwise_fma(whh2[(4*eb+0)*2],   h0v, acc01);
            acc23 = __builtin_elementwise_fma(whh2[(4*eb+0)*2+1], h0v, acc23);
            acc01 = __builtin_elementwise_fma(whh2[(4*eb+1)*2],   h1v, acc01);
            acc23 = __builtin_elementwise_fma(whh2[(4*eb+1)*2+1], h1v, acc23);
            acc01 = __builtin_elementwise_fma(whh2[(4*eb+2)*2],   h2v, acc01);
            acc23 = __builtin_elementwise_fma(whh2[(4*eb+2)*2+1], h2v, acc23);
            acc01 = __builtin_elementwise_fma(whh2[(4*eb+3)*2],   h3v, acc01);
            acc23 = __builtin_elementwise_fma(whh2[(4*eb+3)*2+1], h3v, acc23);
            accP = fmaf(sp.x, h0, accP);
            accP = fmaf(sp.y, h1, accP);
            accP = fmaf(sp.z, h2, accP);
            accP = fmaf(sp.w, h3, accP);
        }
#pragma unroll
        for (int jb = 0; jb < 4; jb++) {
            float4 su = wsu4[(w * 4 + jb) * 64 + lane];   // spread b128
            float tv0 = rl(slice, 32 + 4 * jb);
            float tv1 = rl(slice, 32 + 4 * jb + 1);
            float tv2 = rl(slice, 32 + 4 * jb + 2);
            float tv3 = rl(slice, 32 + 4 * jb + 3);
            f32x2 t0v = {tv0, tv0}, t1v = {tv1, tv1}, t2v = {tv2, tv2}, t3v = {tv3, tv3};
            acc01 = __builtin_elementwise_fma(wsh2[(4*jb+0)*2],   t0v, acc01);
            acc23 = __builtin_elementwise_fma(wsh2[(4*jb+0)*2+1], t0v, acc23);
            acc01 = __builtin_elementwise_fma(wsh2[(4*jb+1)*2],   t1v, acc01);
            acc23 = __builtin_elementwise_fma(wsh2[(4*jb+1)*2+1], t1v, acc23);
            acc01 = __builtin_elementwise_fma(wsh2[(4*jb+2)*2],   t2v, acc01);
            acc23 = __builtin_elementwise_fma(wsh2[(4*jb+2)*2+1], t2v, acc23);
            acc01 = __builtin_elementwise_fma(wsh2[(4*jb+3)*2],   t3v, acc01);
            acc23 = __builtin_elementwise_fma(wsh2[(4*jb+3)*2+1], t3v, acc23);
            accU = fmaf(su.x, tv0, accU);
            accU = fmaf(su.y, tv1, accU);
            accU = fmaf(su.z, tv2, accU);
            accU = fmaf(su.w, tv3, accU);
        }
        *(float4*)&partial[w * 256 + lane * 4] =
            make_float4(acc01.x, acc01.y, acc23.x, acc23.y);
        pp2[w * 64 + lane] = make_float2(accP, accU);   // one b64 write

        // ======== phase B: act logits + gamma dots (waves 0..3, old hid)
        if (w < 4) {
            float bd = 0.f;
#pragma unroll
            for (int k = 0; k < 4; k++)
                bd = fmaf(whaL[w * 256 + k * 64 + lane], hid[k * 64 + lane], bd);
#pragma unroll
            for (int off = 32; off > 0; off >>= 1) bd += __shfl_down(bd, off);
            if (lane == 0) scal[w] = bd + bscal;
        }
        BAR_LDS(); // s1: partials + pp2 + scal visible; all old-state reads done

        // ---- wave 0 alone: push/pop values (only consumed by stack row 0)
        float pvv = 0.f, uvv = 0.f;
        if (w == 0) {
            float v1 = bhs_r, v2 = bsu_r;
#pragma unroll
            for (int q = 0; q < 8; q++) {
                float2 pq = pp2[q * 64 + lane];        // b64 reads
                v1 += pq.x; v2 += pq.y;
            }
            pvv = fmaxf(v1, 0.f);
            uvv = fmaxf(v2, 0.f);
        }

        // ---- hid reduce (waves 4..7 own one h each)
        if (w >= 4) {
            int h = t - 256;
            float mh = exv;
#pragma unroll
            for (int q = 0; q < 8; q++) mh += partial[q * 256 + h];
            float nh = fmaxf(mh, 0.f);
            hid[h] = nh;
            out[((size_t)ts * BATCH + b) * 256 + h] = nh;
        }

        // ---- softmax -> sharpen (fast transcendentals; all threads redundant)
        float4 sc4 = *(const float4*)scal;             // one b128
        float l0 = sc4.x, l1 = sc4.y, l2 = sc4.z, gv = sc4.w;
        float eg = __expf(gv);
        float g = 1.f + ((gv > 15.f) ? gv : __logf(1.f + eg));
        float m = fmaxf(l0, fmaxf(l1, l2));
        float z = __expf(l0 - m) + __expf(l1 - m) + __expf(l2 - m);
        float lz = __logf(z);
        float s0  = __expf(g * (l0 - m - lz));
        float s1v = __expf(g * (l1 - m - lz));
        float s2v = __expf(g * (l2 - m - lz));
        float S = s0 + s1v + s2v + 1e-16f;
        float rS = __builtin_amdgcn_rcpf(S);
        float p0 = s0 * rS, p1 = s1v * rS, p2 = s2v * rS;

        if (t == 0) {
            int am = 0; float bm = s0;
            if (s1v > bm) { bm = s1v; am = 1; }
            if (s2v > bm) { bm = s2v; am = 2; }
            out[ACTS_OFF + ts * BATCH + b] = (float)am;
        }

        // ---- stack blend fully in registers
        {
            float nv[8];
            float below0 = (w == 0) ? pvv : halo_lo;     // push src for row w*8
            float pop0   = (w == 0) ? uvv : sv[1];       // pop src (row 0 gets u_val)
            nv[0] = fmaf(p0, below0, fmaf(p1, pop0, p2 * sv[0]));
#pragma unroll
            for (int k = 1; k < 7; k++)
                nv[k] = fmaf(p0, sv[k - 1], fmaf(p1, sv[k + 1], p2 * sv[k]));
            nv[7] = fmaf(p0, sv[6], fmaf(p1, halo_hi, p2 * sv[7]));
#pragma unroll
            for (int k = 0; k < 8; k++) sv[k] = nv[k];
        }
        // publish new boundary rows (next step's "old" halo) + tops
        bnd[(w * 2) * 64 + lane] = sv[0];
        bnd[(w * 2 + 1) * 64 + lane] = sv[7];
        if (w == 0) { tops[lane] = sv[0]; tops[64 + lane] = sv[1]; }

        exv = exn;
        BAR_LDS(); // s2: new hid/tops/bnd visible for next step
    }

    // ---- final hid & stack
    if (t < 256) out[HID_OFF + (size_t)b * 256 + t] = hid[t];
#pragma unroll
    for (int k = 0; k < 8; k++)
        out[STACK_OFF + (size_t)b * 4096 + (w * 8 + k) * 64 + lane] = sv[k];
}

// ---------------- launcher ---------------------------------------------------
extern "C" void kernel_launch(void* const* d_in, const int* in_sizes, int n_in,
                              void* d_out, int out_size, void* d_ws, size_t ws_size,
                              hipStream_t stream)
{
    (void)in_sizes; (void)n_in; (void)out_size; (void)ws_size;
    const int*   inputs     = (const int*)d_in[0];
    const float* emb_W      = (const float*)d_in[1];
    const float* W_hh       = (const float*)d_in[2];
    const float* b_hh       = (const float*)d_in[3];
    const float* W_eh       = (const float*)d_in[4];
    const float* b_eh       = (const float*)d_in[5];
    const float* W_ha       = (const float*)d_in[6];
    const float* b_ha       = (const float*)d_in[7];
    const float* W_hg       = (const float*)d_in[8];
    const float* b_hg       = (const float*)d_in[9];
    const float* W_hs       = (const float*)d_in[10];
    const float* b_hs       = (const float*)d_in[11];
    const float* W_sh       = (const float*)d_in[12];
    const float* b_sh       = (const float*)d_in[13];
    const float* W_su       = (const float*)d_in[14];
    const float* b_su       = (const float*)d_in[15];
    const float* empty_elem = (const float*)d_in[16];
    float* out = (float*)d_out;
    float* ws  = (float*)d_ws;

    hipLaunchKernelGGL(prep_kernel, dim3(737), dim3(256), 0, stream,
                       W_hh, b_hh, W_eh, b_eh, W_sh, b_sh, W_hs, W_su, ws);
    hipLaunchKernelGGL(ex_gemm, dim3(1024), dim3(256), 0, stream,
                       inputs, emb_W, ws, out);
    hipLaunchKernelGGL(rnn_scan, dim3(128), dim3(512), 0, stream,
                       ws, W_ha, b_ha, W_hg, b_hg, b_hs, b_su, empty_elem, out);
}